// Round 2
// baseline (2588.889 us; speedup 1.0000x reference)
//
#include <hip/hip_runtime.h>

// Problem constants
// B=64, L=196, CV=2048, T=20 (19 steps), VOCAB=10000, E=H=A=512, 4H=2048
//
// Memory plan:
//  d_out (12.16M floats, written only by the final gemm_logits) doubles as
//  scratch for the two big early buffers:
//    k         [12544,512]  at out+0         (6,422,528 floats)
//    gates_emb [1216,2048]  at out+SZ_K      (2,490,368 floats)  sum < 12.16M
//  d_ws holds only the small recurrent state (~8.2 MB):

#define SZ_K     (12544ull*512)
#define SZ_GE    (1216ull*2048)

#define SZ_HALL  (1216ull*512)         // all h_t               [19*64, 512]
#define SZ_X2    (64ull*2560)          // [ctx | h] per batch   [64, 2560]
#define SZ_H     (32768ull)            // h  [64,512]
#define SZ_C     (32768ull)            // c  [64,512]
#define SZ_QP    (4ull*64*512)         // q split-K partials    [4][64][512]
#define SZ_PART  (8ull*64*2048)        // gates split-K partials[8][64][2048]

#define OFF_HALL 0ull
#define OFF_X2   (OFF_HALL + SZ_HALL)
#define OFF_H    (OFF_X2 + SZ_X2)
#define OFF_C    (OFF_H + SZ_H)
#define OFF_QP   (OFF_C + SZ_C)
#define OFF_PART (OFF_QP + SZ_QP)
#define OFF_AB   (OFF_PART + SZ_PART)  // attention weights [64,196]
// total ws floats = 2,044,160  (~8.2 MB)

__device__ __forceinline__ float ftanh(float x) {
    x = fminf(fmaxf(x, -15.f), 15.f);
    float e = __expf(2.f * x);
    return (e - 1.f) / (e + 1.f);
}
__device__ __forceinline__ float fsig(float x) {
    x = fminf(fmaxf(x, -30.f), 30.f);
    return 1.f / (1.f + __expf(-x));
}

// ---------------- init: zero h, c, h-part of x2 ----------------
__global__ void init_state(float* __restrict__ ws) {
    const int b = blockIdx.x, tid = threadIdx.x;
    float* h  = ws + OFF_H;
    float* c  = ws + OFF_C;
    float* x2 = ws + OFF_X2;
    for (int j = tid; j < 512; j += 256) {
        h[b * 512 + j] = 0.f;
        c[b * 512 + j] = 0.f;
        x2[b * 2560 + 2048 + j] = 0.f;
    }
}

// ---------------- k = V @ Wv^T + Wv_b  (M=12544,N=512,K=2048) ----------------
__global__ __launch_bounds__(256)
void gemm_k(const float* __restrict__ V, const float* __restrict__ Wv,
            const float* __restrict__ bv, float* __restrict__ kout) {
    const int m0 = blockIdx.x * 64;
    const int n0 = blockIdx.y * 64;
    __shared__ float As[32][68];
    __shared__ float Bs[32][68];
    const int tid = threadIdx.x;
    const int tx = tid & 15, ty = tid >> 4;
    float acc[4][4] = {{0.f}};
    for (int k0 = 0; k0 < 2048; k0 += 32) {
#pragma unroll
        for (int i = 0; i < 2; ++i) {
            int idx = tid + i * 256;
            int m = idx >> 3, cc = idx & 7;
            float4 av = *reinterpret_cast<const float4*>(V + (size_t)(m0 + m) * 2048 + k0 + cc * 4);
            As[cc * 4 + 0][m] = av.x; As[cc * 4 + 1][m] = av.y;
            As[cc * 4 + 2][m] = av.z; As[cc * 4 + 3][m] = av.w;
            float4 bw = *reinterpret_cast<const float4*>(Wv + (size_t)(n0 + m) * 2048 + k0 + cc * 4);
            Bs[cc * 4 + 0][m] = bw.x; Bs[cc * 4 + 1][m] = bw.y;
            Bs[cc * 4 + 2][m] = bw.z; Bs[cc * 4 + 3][m] = bw.w;
        }
        __syncthreads();
#pragma unroll
        for (int kk = 0; kk < 32; ++kk) {
            float4 a4 = *reinterpret_cast<const float4*>(&As[kk][ty * 4]);
            float4 b4 = *reinterpret_cast<const float4*>(&Bs[kk][tx * 4]);
            float ar[4] = {a4.x, a4.y, a4.z, a4.w};
            float br[4] = {b4.x, b4.y, b4.z, b4.w};
#pragma unroll
            for (int i2 = 0; i2 < 4; ++i2)
#pragma unroll
                for (int j2 = 0; j2 < 4; ++j2)
                    acc[i2][j2] = fmaf(ar[i2], br[j2], acc[i2][j2]);
        }
        __syncthreads();
    }
#pragma unroll
    for (int i2 = 0; i2 < 4; ++i2) {
        int m = m0 + ty * 4 + i2;
        int n = n0 + tx * 4;
        float4 o;
        o.x = acc[i2][0] + bv[n + 0]; o.y = acc[i2][1] + bv[n + 1];
        o.z = acc[i2][2] + bv[n + 2]; o.w = acc[i2][3] + bv[n + 3];
        *reinterpret_cast<float4*>(kout + (size_t)m * 512 + n) = o;
    }
}

// ------- gates_emb[t,b,:] = embed[caps[b,t]] @ W_ih[:, :512]^T + b_ih + b_hh -------
__global__ __launch_bounds__(256)
void gemm_emb(const float* __restrict__ embW, const int* __restrict__ caps,
              const float* __restrict__ Wih, const float* __restrict__ bih,
              const float* __restrict__ bhh, float* __restrict__ ge) {
    const int t = blockIdx.x;        // 19
    const int n0 = blockIdx.y * 64;  // 32
    __shared__ float As[32][68];
    __shared__ float Bs[32][68];
    __shared__ int capss[64];
    const int tid = threadIdx.x;
    const int tx = tid & 15, ty = tid >> 4;
    if (tid < 64) capss[tid] = caps[tid * 20 + t];
    __syncthreads();
    float acc[4][4] = {{0.f}};
    for (int k0 = 0; k0 < 512; k0 += 32) {
#pragma unroll
        for (int i = 0; i < 2; ++i) {
            int idx = tid + i * 256;
            int m = idx >> 3, cc = idx & 7;
            float4 av = *reinterpret_cast<const float4*>(embW + (size_t)capss[m] * 512 + k0 + cc * 4);
            As[cc * 4 + 0][m] = av.x; As[cc * 4 + 1][m] = av.y;
            As[cc * 4 + 2][m] = av.z; As[cc * 4 + 3][m] = av.w;
            float4 bw = *reinterpret_cast<const float4*>(Wih + (size_t)(n0 + m) * 2560 + k0 + cc * 4);
            Bs[cc * 4 + 0][m] = bw.x; Bs[cc * 4 + 1][m] = bw.y;
            Bs[cc * 4 + 2][m] = bw.z; Bs[cc * 4 + 3][m] = bw.w;
        }
        __syncthreads();
#pragma unroll
        for (int kk = 0; kk < 32; ++kk) {
            float4 a4 = *reinterpret_cast<const float4*>(&As[kk][ty * 4]);
            float4 b4 = *reinterpret_cast<const float4*>(&Bs[kk][tx * 4]);
            float ar[4] = {a4.x, a4.y, a4.z, a4.w};
            float br[4] = {b4.x, b4.y, b4.z, b4.w};
#pragma unroll
            for (int i2 = 0; i2 < 4; ++i2)
#pragma unroll
                for (int j2 = 0; j2 < 4; ++j2)
                    acc[i2][j2] = fmaf(ar[i2], br[j2], acc[i2][j2]);
        }
        __syncthreads();
    }
#pragma unroll
    for (int i2 = 0; i2 < 4; ++i2) {
        int m = ty * 4 + i2;
        int n = n0 + tx * 4;
        float4 o;
        o.x = acc[i2][0] + bih[n + 0] + bhh[n + 0];
        o.y = acc[i2][1] + bih[n + 1] + bhh[n + 1];
        o.z = acc[i2][2] + bih[n + 2] + bhh[n + 2];
        o.w = acc[i2][3] + bih[n + 3] + bhh[n + 3];
        *reinterpret_cast<float4*>(ge + (size_t)(t * 64 + m) * 2048 + n) = o;
    }
}

// ---------------- q partials: qp[p] = h @ Wh^T over K-chunk p (M=64,N=512,K=512) ----------------
__global__ __launch_bounds__(256)
void kq_gemm(const float* __restrict__ Whw, float* __restrict__ ws) {
    const float* h = ws + OFF_H;
    float* qp = ws + OFF_QP;
    const int n0 = blockIdx.x * 64;  // 8
    const int kc = blockIdx.y;       // 4  -> K in [kc*128, kc*128+128)
    __shared__ float As[32][68];
    __shared__ float Bs[32][68];
    const int tid = threadIdx.x;
    const int tx = tid & 15, ty = tid >> 4;
    float acc[4][4] = {{0.f}};
    for (int kt = 0; kt < 4; ++kt) {
        int kb = kc * 128 + kt * 32;
#pragma unroll
        for (int i = 0; i < 2; ++i) {
            int idx = tid + i * 256;
            int m = idx >> 3, cc = idx & 7;
            float4 av = *reinterpret_cast<const float4*>(h + (size_t)m * 512 + kb + cc * 4);
            As[cc * 4 + 0][m] = av.x; As[cc * 4 + 1][m] = av.y;
            As[cc * 4 + 2][m] = av.z; As[cc * 4 + 3][m] = av.w;
            float4 bw = *reinterpret_cast<const float4*>(Whw + (size_t)(n0 + m) * 512 + kb + cc * 4);
            Bs[cc * 4 + 0][m] = bw.x; Bs[cc * 4 + 1][m] = bw.y;
            Bs[cc * 4 + 2][m] = bw.z; Bs[cc * 4 + 3][m] = bw.w;
        }
        __syncthreads();
#pragma unroll
        for (int kk = 0; kk < 32; ++kk) {
            float4 a4 = *reinterpret_cast<const float4*>(&As[kk][ty * 4]);
            float4 b4 = *reinterpret_cast<const float4*>(&Bs[kk][tx * 4]);
            float ar[4] = {a4.x, a4.y, a4.z, a4.w};
            float br[4] = {b4.x, b4.y, b4.z, b4.w};
#pragma unroll
            for (int i2 = 0; i2 < 4; ++i2)
#pragma unroll
                for (int j2 = 0; j2 < 4; ++j2)
                    acc[i2][j2] = fmaf(ar[i2], br[j2], acc[i2][j2]);
        }
        __syncthreads();
    }
#pragma unroll
    for (int i2 = 0; i2 < 4; ++i2) {
        int b = ty * 4 + i2;
        int n = n0 + tx * 4;
        float4 o = make_float4(acc[i2][0], acc[i2][1], acc[i2][2], acc[i2][3]);
        *reinterpret_cast<float4*>(qp + (size_t)(kc * 64 + b) * 512 + n) = o;
    }
}

// ---------------- attention: e = v . tanh(q+k), softmax -> abuf ----------------
__global__ __launch_bounds__(256)
void attn_step(const float* __restrict__ Whb, const float* __restrict__ vw,
               float* __restrict__ ws, const float* __restrict__ kbuf) {
    const int b = blockIdx.x, tid = threadIdx.x;
    const float* qp = ws + OFF_QP;
    float* abuf = ws + OFF_AB;
    __shared__ float qs[512];
    __shared__ float vs[512];
    __shared__ float es[196];
    __shared__ float red[256];
    for (int j = tid; j < 512; j += 256) {
        float q = Whb[j];
#pragma unroll
        for (int p = 0; p < 4; ++p) q += qp[(size_t)(p * 64 + b) * 512 + j];
        qs[j] = q;
        vs[j] = vw[j];
    }
    __syncthreads();
    const int w = tid >> 6, lane = tid & 63;
    for (int l = w; l < 196; l += 4) {
        const float* kr = kbuf + (size_t)(b * 196 + l) * 512;
        float s = 0.f;
#pragma unroll
        for (int ii = 0; ii < 8; ++ii) {
            int a = lane + ii * 64;
            s += vs[a] * ftanh(qs[a] + kr[a]);
        }
#pragma unroll
        for (int mm = 32; mm >= 1; mm >>= 1) s += __shfl_xor(s, mm);
        if (lane == 0) es[l] = s;
    }
    __syncthreads();
    float ev = (tid < 196) ? es[tid] : -1e30f;
    red[tid] = ev;
    __syncthreads();
    for (int s2 = 128; s2 > 0; s2 >>= 1) {
        if (tid < s2) red[tid] = fmaxf(red[tid], red[tid + s2]);
        __syncthreads();
    }
    float mx = red[0];
    __syncthreads();
    float p = (tid < 196) ? __expf(ev - mx) : 0.f;
    red[tid] = p;
    __syncthreads();
    for (int s2 = 128; s2 > 0; s2 >>= 1) {
        if (tid < s2) red[tid] += red[tid + s2];
        __syncthreads();
    }
    float inv = 1.f / red[0];
    if (tid < 196) abuf[b * 196 + tid] = p * inv;
}

// ---------------- ctx[b,c] = sum_l a[b,l] * V[b,l,c]  -> x2[:, :2048] ----------------
__global__ __launch_bounds__(256)
void ctx_step(const float* __restrict__ V, float* __restrict__ ws) {
    const int b = blockIdx.y, tid = threadIdx.x;
    const int c = blockIdx.x * 256 + tid;
    const float* abuf = ws + OFF_AB;
    float* x2 = ws + OFF_X2;
    __shared__ float as_[196];
    if (tid < 196) as_[tid] = abuf[b * 196 + tid];
    __syncthreads();
    const float* vb = V + (size_t)b * 196 * 2048 + c;
    float a0 = 0.f, a1 = 0.f, a2 = 0.f, a3 = 0.f;
    for (int l = 0; l < 196; l += 4) {
        a0 = fmaf(as_[l + 0], vb[(size_t)(l + 0) * 2048], a0);
        a1 = fmaf(as_[l + 1], vb[(size_t)(l + 1) * 2048], a1);
        a2 = fmaf(as_[l + 2], vb[(size_t)(l + 2) * 2048], a2);
        a3 = fmaf(as_[l + 3], vb[(size_t)(l + 3) * 2048], a3);
    }
    x2[b * 2560 + c] = (a0 + a1) + (a2 + a3);
}

// ------- gates partials: part[kc] = x2 @ [W_ih[:,512:] | W_hh]^T over K-chunk kc -------
__global__ __launch_bounds__(256)
void gates_gemm(const float* __restrict__ Wih, const float* __restrict__ Whh,
                float* __restrict__ ws) {
    const float* x2 = ws + OFF_X2;
    float* part = ws + OFF_PART;
    const int n0 = blockIdx.x * 64;  // 32 blocks -> gate rows
    const int kc = blockIdx.y;       // 8  -> K in [kc*320, kc*320+320)
    __shared__ float As[32][68];
    __shared__ float Bs[32][68];
    const int tid = threadIdx.x;
    const int tx = tid & 15, ty = tid >> 4;
    float acc[4][4] = {{0.f}};
    for (int kt = 0; kt < 10; ++kt) {
        int kb = kc * 320 + kt * 32;
#pragma unroll
        for (int i = 0; i < 2; ++i) {
            int idx = tid + i * 256;
            int m = idx >> 3, cc = idx & 7;
            int kg = kb + cc * 4;
            float4 av = *reinterpret_cast<const float4*>(x2 + (size_t)m * 2560 + kg);
            As[cc * 4 + 0][m] = av.x; As[cc * 4 + 1][m] = av.y;
            As[cc * 4 + 2][m] = av.z; As[cc * 4 + 3][m] = av.w;
            int j = n0 + m;
            float4 bw;
            if (kg < 2048)
                bw = *reinterpret_cast<const float4*>(Wih + (size_t)j * 2560 + 512 + kg);
            else
                bw = *reinterpret_cast<const float4*>(Whh + (size_t)j * 512 + (kg - 2048));
            Bs[cc * 4 + 0][m] = bw.x; Bs[cc * 4 + 1][m] = bw.y;
            Bs[cc * 4 + 2][m] = bw.z; Bs[cc * 4 + 3][m] = bw.w;
        }
        __syncthreads();
#pragma unroll
        for (int kk = 0; kk < 32; ++kk) {
            float4 a4 = *reinterpret_cast<const float4*>(&As[kk][ty * 4]);
            float4 b4 = *reinterpret_cast<const float4*>(&Bs[kk][tx * 4]);
            float ar[4] = {a4.x, a4.y, a4.z, a4.w};
            float br[4] = {b4.x, b4.y, b4.z, b4.w};
#pragma unroll
            for (int i2 = 0; i2 < 4; ++i2)
#pragma unroll
                for (int j2 = 0; j2 < 4; ++j2)
                    acc[i2][j2] = fmaf(ar[i2], br[j2], acc[i2][j2]);
        }
        __syncthreads();
    }
#pragma unroll
    for (int i2 = 0; i2 < 4; ++i2) {
        int b = ty * 4 + i2;
        int n = n0 + tx * 4;
        float4 o = make_float4(acc[i2][0], acc[i2][1], acc[i2][2], acc[i2][3]);
        *reinterpret_cast<float4*>(part + (size_t)(kc * 64 + b) * 2048 + n) = o;
    }
}

// ---------------- LSTM pointwise: gates -> h_new, c_new ----------------
__global__ __launch_bounds__(256)
void lstm_step(float* __restrict__ ws, const float* __restrict__ geb, int t) {
    const int b = blockIdx.x;
    const int j = blockIdx.y * 256 + threadIdx.x;
    const float* ge = geb + (size_t)(t * 64 + b) * 2048;
    const float* part = ws + OFF_PART;
    float* h = ws + OFF_H;
    float* c = ws + OFF_C;
    float* x2 = ws + OFF_X2;
    float* hall = ws + OFF_HALL;
    float ig = ge[j], fg = ge[512 + j], gg = ge[1024 + j], og = ge[1536 + j];
#pragma unroll
    for (int p = 0; p < 8; ++p) {
        const float* pp = part + (size_t)(p * 64 + b) * 2048;
        ig += pp[j]; fg += pp[512 + j]; gg += pp[1024 + j]; og += pp[1536 + j];
    }
    float cv = fsig(fg) * c[b * 512 + j] + fsig(ig) * ftanh(gg);
    float hv = fsig(og) * ftanh(cv);
    c[b * 512 + j] = cv;
    h[b * 512 + j] = hv;
    x2[b * 2560 + 2048 + j] = hv;
    hall[(size_t)(t * 64 + b) * 512 + j] = hv;
}

// ---------------- logits = hall @ out_w^T + out_b  (M=1216,N=10000,K=512) ----------------
__global__ __launch_bounds__(256)
void gemm_logits(const float* __restrict__ outw, const float* __restrict__ outb,
                 const float* __restrict__ ws, float* __restrict__ out) {
    const float* hall = ws + OFF_HALL;
    const int t = blockIdx.x;        // 19
    const int n0 = blockIdx.y * 64;  // 157
    __shared__ float As[32][68];
    __shared__ float Bs[32][68];
    const int tid = threadIdx.x;
    const int tx = tid & 15, ty = tid >> 4;
    float acc[4][4] = {{0.f}};
    for (int k0 = 0; k0 < 512; k0 += 32) {
#pragma unroll
        for (int i = 0; i < 2; ++i) {
            int idx = tid + i * 256;
            int m = idx >> 3, cc = idx & 7;
            float4 av = *reinterpret_cast<const float4*>(hall + (size_t)(t * 64 + m) * 512 + k0 + cc * 4);
            As[cc * 4 + 0][m] = av.x; As[cc * 4 + 1][m] = av.y;
            As[cc * 4 + 2][m] = av.z; As[cc * 4 + 3][m] = av.w;
            int j = n0 + m; if (j > 9999) j = 9999;
            float4 bw = *reinterpret_cast<const float4*>(outw + (size_t)j * 512 + k0 + cc * 4);
            Bs[cc * 4 + 0][m] = bw.x; Bs[cc * 4 + 1][m] = bw.y;
            Bs[cc * 4 + 2][m] = bw.z; Bs[cc * 4 + 3][m] = bw.w;
        }
        __syncthreads();
#pragma unroll
        for (int kk = 0; kk < 32; ++kk) {
            float4 a4 = *reinterpret_cast<const float4*>(&As[kk][ty * 4]);
            float4 b4 = *reinterpret_cast<const float4*>(&Bs[kk][tx * 4]);
            float ar[4] = {a4.x, a4.y, a4.z, a4.w};
            float br[4] = {b4.x, b4.y, b4.z, b4.w};
#pragma unroll
            for (int i2 = 0; i2 < 4; ++i2)
#pragma unroll
                for (int j2 = 0; j2 < 4; ++j2)
                    acc[i2][j2] = fmaf(ar[i2], br[j2], acc[i2][j2]);
        }
        __syncthreads();
    }
#pragma unroll
    for (int i2 = 0; i2 < 4; ++i2) {
        int b = ty * 4 + i2;
        int n = n0 + tx * 4;
        if (n < 10000) {
            float4 o;
            o.x = acc[i2][0] + outb[n + 0]; o.y = acc[i2][1] + outb[n + 1];
            o.z = acc[i2][2] + outb[n + 2]; o.w = acc[i2][3] + outb[n + 3];
            *reinterpret_cast<float4*>(out + ((size_t)b * 19 + t) * 10000 + n) = o;
        }
    }
}

extern "C" void kernel_launch(void* const* d_in, const int* in_sizes, int n_in,
                              void* d_out, int out_size, void* d_ws, size_t ws_size,
                              hipStream_t stream) {
    const float* V    = (const float*)d_in[0];
    const int*   caps = (const int*)d_in[1];
    const float* embW = (const float*)d_in[2];
    const float* Whw  = (const float*)d_in[3];
    const float* Whb  = (const float*)d_in[4];
    const float* Wvw  = (const float*)d_in[5];
    const float* Wvb  = (const float*)d_in[6];
    const float* vw   = (const float*)d_in[7];
    // d_in[8] = v_b: additive constant inside softmax -> cancels, unused
    const float* Wih  = (const float*)d_in[9];
    const float* Whh  = (const float*)d_in[10];
    const float* bih  = (const float*)d_in[11];
    const float* bhh  = (const float*)d_in[12];
    const float* outw = (const float*)d_in[13];
    const float* outb = (const float*)d_in[14];
    float* ws  = (float*)d_ws;
    float* out = (float*)d_out;

    // big dead-by-the-end buffers live in d_out (overwritten by gemm_logits)
    float* kbuf = out;             // [12544,512]
    float* gebuf = out + SZ_K;     // [19*64,2048]

    init_state<<<dim3(64), dim3(256), 0, stream>>>(ws);
    gemm_k<<<dim3(196, 8), dim3(256), 0, stream>>>(V, Wvw, Wvb, kbuf);
    gemm_emb<<<dim3(19, 32), dim3(256), 0, stream>>>(embW, caps, Wih, bih, bhh, gebuf);

    for (int t = 0; t < 19; ++t) {
        kq_gemm<<<dim3(8, 4), dim3(256), 0, stream>>>(Whw, ws);
        attn_step<<<dim3(64), dim3(256), 0, stream>>>(Whb, vw, ws, kbuf);
        ctx_step<<<dim3(8, 64), dim3(256), 0, stream>>>(V, ws);
        gates_gemm<<<dim3(32, 8), dim3(256), 0, stream>>>(Wih, Whh, ws);
        lstm_step<<<dim3(64, 2), dim3(256), 0, stream>>>(ws, gebuf, t);
    }

    gemm_logits<<<dim3(19, 157), dim3(256), 0, stream>>>(outw, outb, ws, out);
}

// Round 3
// 1977.008 us; speedup vs baseline: 1.3095x; 1.3095x over previous
//
#include <hip/hip_runtime.h>

// B=64, L=196, CV=2048, T=20 (19 steps), VOCAB=10000, E=H=A=512, 4H=2048
// bf16-MFMA round: all big GEMMs on matrix cores, fp32 recurrent state.

typedef __bf16 bf16x8 __attribute__((ext_vector_type(8)));
typedef float f32x4 __attribute__((ext_vector_type(4)));
typedef unsigned short ushort8 __attribute__((ext_vector_type(8)));

// ---------------- workspace layout (float offsets), total 5.70 MB ----------------
#define OFF_HALL 0ull                   // hall fp32 [19*64][512]  = 622592 f
#define OFF_X2H  622592ull              // x2h bf16 [64][2560]     = 81920 f-equiv
#define OFF_H    704512ull              // h fp32 [64][512]
#define OFF_C    737280ull              // c fp32 [64][512]
#define OFF_QP   770048ull              // q split-K partials fp32 [4][64][512]
#define OFF_PART 901120ull              // gates split-K partials fp32 [4][64][2048]
// end = 1,425,408 floats

// ---------------- d_out scrap layout (float offsets; dead before gemm_logits) ----
#define D_WGH 0ull                      // Wg bf16 [2048][2560] = 2,621,440 f-equiv
#define D_GE  2621440ull                // gates_emb fp32 [19*64][2048] = 2,490,368 f
#define D_KB  5111808ull                // k bf16 [12544][512] = 3,211,264 f-equiv
// end = 8,323,072 <= 12,160,000

__device__ __forceinline__ unsigned short f2bf(float f) {
    unsigned int u = __float_as_uint(f);
    unsigned int r = u + 0x7FFFu + ((u >> 16) & 1u);
    return (unsigned short)(r >> 16);
}
__device__ __forceinline__ float bf2f(unsigned short h) {
    return __uint_as_float(((unsigned int)h) << 16);
}
__device__ __forceinline__ float ftanh(float x) {
    x = fminf(fmaxf(x, -15.f), 15.f);
    float e = __expf(2.f * x);
    return (e - 1.f) / (e + 1.f);
}
__device__ __forceinline__ float fsig(float x) {
    x = fminf(fmaxf(x, -30.f), 30.f);
    return 1.f / (1.f + __expf(-x));
}

// ---------------- init: zero h, c, x2h h-part ----------------
__global__ void init_state(float* __restrict__ ws) {
    const int b = blockIdx.x, tid = threadIdx.x;
    float* h  = ws + OFF_H;
    float* c  = ws + OFF_C;
    unsigned short* x2h = (unsigned short*)(ws + OFF_X2H);
    for (int j = tid; j < 512; j += 256) {
        h[b * 512 + j] = 0.f;
        c[b * 512 + j] = 0.f;
        x2h[b * 2560 + 2048 + j] = 0;
    }
}

// ---------------- Wg bf16 = [Wih[:,512:] | Whh]  [2048][2560] ----------------
__global__ __launch_bounds__(256)
void conv_wg(const float* __restrict__ Wih, const float* __restrict__ Whh,
             unsigned short* __restrict__ Wgh) {
    const int idx = blockIdx.x * 256 + threadIdx.x;   // 2560 blocks, 8 elems each
    const int j = idx / 320;
    const int c0 = (idx - j * 320) * 8;
    const float* src;
    if (c0 < 2048) src = Wih + (size_t)j * 2560 + 512 + c0;
    else           src = Whh + (size_t)j * 512 + (c0 - 2048);
    float4 a = *reinterpret_cast<const float4*>(src);
    float4 b = *reinterpret_cast<const float4*>(src + 4);
    ushort8 o;
    o[0]=f2bf(a.x); o[1]=f2bf(a.y); o[2]=f2bf(a.z); o[3]=f2bf(a.w);
    o[4]=f2bf(b.x); o[5]=f2bf(b.y); o[6]=f2bf(b.z); o[7]=f2bf(b.w);
    *reinterpret_cast<ushort8*>(Wgh + (size_t)j * 2560 + c0) = o;
}

// ---------------- k = V @ Wv^T + bv  (MFMA bf16, out bf16) ----------------
// M=12544 N=512 K=2048, tile 64x64, BK=32, 4 waves (2x2 of 32x32)
__global__ __launch_bounds__(256)
void gemm_k_mfma(const float* __restrict__ V, const float* __restrict__ Wv,
                 const float* __restrict__ bv, unsigned short* __restrict__ kout) {
    __shared__ unsigned short At[64 * 32];
    __shared__ unsigned short Bt[64 * 32];
    const int tid = threadIdx.x;
    const int lane = tid & 63, wave = tid >> 6;
    const int wr = wave >> 1, wc = wave & 1;
    const int m0 = blockIdx.x * 64, n0 = blockIdx.y * 64;
    const int srow = tid >> 2, skg = tid & 3;
    const float* ga = V  + (size_t)(m0 + srow) * 2048 + skg * 8;
    const float* gb = Wv + (size_t)(n0 + srow) * 2048 + skg * 8;
    const int ar0 = (wr * 32 + (lane & 15)) * 32 + (lane >> 4) * 8;
    const int br0 = (wc * 32 + (lane & 15)) * 32 + (lane >> 4) * 8;
    f32x4 acc[2][2] = {};
    for (int k0 = 0; k0 < 2048; k0 += 32) {
        float4 a0 = *reinterpret_cast<const float4*>(ga + k0);
        float4 a1 = *reinterpret_cast<const float4*>(ga + k0 + 4);
        float4 b0 = *reinterpret_cast<const float4*>(gb + k0);
        float4 b1 = *reinterpret_cast<const float4*>(gb + k0 + 4);
        ushort8 ua, ub;
        ua[0]=f2bf(a0.x); ua[1]=f2bf(a0.y); ua[2]=f2bf(a0.z); ua[3]=f2bf(a0.w);
        ua[4]=f2bf(a1.x); ua[5]=f2bf(a1.y); ua[6]=f2bf(a1.z); ua[7]=f2bf(a1.w);
        ub[0]=f2bf(b0.x); ub[1]=f2bf(b0.y); ub[2]=f2bf(b0.z); ub[3]=f2bf(b0.w);
        ub[4]=f2bf(b1.x); ub[5]=f2bf(b1.y); ub[6]=f2bf(b1.z); ub[7]=f2bf(b1.w);
        *reinterpret_cast<ushort8*>(&At[tid * 8]) = ua;
        *reinterpret_cast<ushort8*>(&Bt[tid * 8]) = ub;
        __syncthreads();
        bf16x8 af0 = *reinterpret_cast<const bf16x8*>(&At[ar0]);
        bf16x8 af1 = *reinterpret_cast<const bf16x8*>(&At[ar0 + 16 * 32]);
        bf16x8 bf0 = *reinterpret_cast<const bf16x8*>(&Bt[br0]);
        bf16x8 bf1 = *reinterpret_cast<const bf16x8*>(&Bt[br0 + 16 * 32]);
        acc[0][0] = __builtin_amdgcn_mfma_f32_16x16x32_bf16(af0, bf0, acc[0][0], 0, 0, 0);
        acc[0][1] = __builtin_amdgcn_mfma_f32_16x16x32_bf16(af0, bf1, acc[0][1], 0, 0, 0);
        acc[1][0] = __builtin_amdgcn_mfma_f32_16x16x32_bf16(af1, bf0, acc[1][0], 0, 0, 0);
        acc[1][1] = __builtin_amdgcn_mfma_f32_16x16x32_bf16(af1, bf1, acc[1][1], 0, 0, 0);
        __syncthreads();
    }
#pragma unroll
    for (int fi = 0; fi < 2; ++fi)
#pragma unroll
        for (int fj = 0; fj < 2; ++fj)
#pragma unroll
            for (int r = 0; r < 4; ++r) {
                int m = m0 + wr * 32 + fi * 16 + (lane >> 4) * 4 + r;
                int n = n0 + wc * 32 + fj * 16 + (lane & 15);
                kout[(size_t)m * 512 + n] = f2bf(acc[fi][fj][r] + bv[n]);
            }
}

// ------- gates_emb[t,b,:] = embed[caps[b,t]] @ W_ih[:, :512]^T + b_ih + b_hh (fp32) -------
__global__ __launch_bounds__(256)
void gemm_emb(const float* __restrict__ embW, const int* __restrict__ caps,
              const float* __restrict__ Wih, const float* __restrict__ bih,
              const float* __restrict__ bhh, float* __restrict__ ge) {
    const int t = blockIdx.x;        // 19
    const int n0 = blockIdx.y * 64;  // 32
    __shared__ float As[32][68];
    __shared__ float Bs[32][68];
    __shared__ int capss[64];
    const int tid = threadIdx.x;
    const int tx = tid & 15, ty = tid >> 4;
    if (tid < 64) capss[tid] = caps[tid * 20 + t];
    __syncthreads();
    float acc[4][4] = {{0.f}};
    for (int k0 = 0; k0 < 512; k0 += 32) {
#pragma unroll
        for (int i = 0; i < 2; ++i) {
            int idx = tid + i * 256;
            int m = idx >> 3, cc = idx & 7;
            float4 av = *reinterpret_cast<const float4*>(embW + (size_t)capss[m] * 512 + k0 + cc * 4);
            As[cc * 4 + 0][m] = av.x; As[cc * 4 + 1][m] = av.y;
            As[cc * 4 + 2][m] = av.z; As[cc * 4 + 3][m] = av.w;
            float4 bw = *reinterpret_cast<const float4*>(Wih + (size_t)(n0 + m) * 2560 + k0 + cc * 4);
            Bs[cc * 4 + 0][m] = bw.x; Bs[cc * 4 + 1][m] = bw.y;
            Bs[cc * 4 + 2][m] = bw.z; Bs[cc * 4 + 3][m] = bw.w;
        }
        __syncthreads();
#pragma unroll
        for (int kk = 0; kk < 32; ++kk) {
            float4 a4 = *reinterpret_cast<const float4*>(&As[kk][ty * 4]);
            float4 b4 = *reinterpret_cast<const float4*>(&Bs[kk][tx * 4]);
            float ar[4] = {a4.x, a4.y, a4.z, a4.w};
            float br[4] = {b4.x, b4.y, b4.z, b4.w};
#pragma unroll
            for (int i2 = 0; i2 < 4; ++i2)
#pragma unroll
                for (int j2 = 0; j2 < 4; ++j2)
                    acc[i2][j2] = fmaf(ar[i2], br[j2], acc[i2][j2]);
        }
        __syncthreads();
    }
#pragma unroll
    for (int i2 = 0; i2 < 4; ++i2) {
        int m = ty * 4 + i2;
        int n = n0 + tx * 4;
        float4 o;
        o.x = acc[i2][0] + bih[n + 0] + bhh[n + 0];
        o.y = acc[i2][1] + bih[n + 1] + bhh[n + 1];
        o.z = acc[i2][2] + bih[n + 2] + bhh[n + 2];
        o.w = acc[i2][3] + bih[n + 3] + bhh[n + 3];
        *reinterpret_cast<float4*>(ge + (size_t)(t * 64 + m) * 2048 + n) = o;
    }
}

// ---------------- q partials (fp32): qp[p] = h @ Wh^T over K-chunk p ----------------
__global__ __launch_bounds__(256)
void kq_gemm(const float* __restrict__ Whw, float* __restrict__ ws) {
    const float* h = ws + OFF_H;
    float* qp = ws + OFF_QP;
    const int n0 = blockIdx.x * 64;  // 8
    const int kc = blockIdx.y;       // 4
    __shared__ float As[32][68];
    __shared__ float Bs[32][68];
    const int tid = threadIdx.x;
    const int tx = tid & 15, ty = tid >> 4;
    float acc[4][4] = {{0.f}};
    for (int kt = 0; kt < 4; ++kt) {
        int kb = kc * 128 + kt * 32;
#pragma unroll
        for (int i = 0; i < 2; ++i) {
            int idx = tid + i * 256;
            int m = idx >> 3, cc = idx & 7;
            float4 av = *reinterpret_cast<const float4*>(h + (size_t)m * 512 + kb + cc * 4);
            As[cc * 4 + 0][m] = av.x; As[cc * 4 + 1][m] = av.y;
            As[cc * 4 + 2][m] = av.z; As[cc * 4 + 3][m] = av.w;
            float4 bw = *reinterpret_cast<const float4*>(Whw + (size_t)(n0 + m) * 512 + kb + cc * 4);
            Bs[cc * 4 + 0][m] = bw.x; Bs[cc * 4 + 1][m] = bw.y;
            Bs[cc * 4 + 2][m] = bw.z; Bs[cc * 4 + 3][m] = bw.w;
        }
        __syncthreads();
#pragma unroll
        for (int kk = 0; kk < 32; ++kk) {
            float4 a4 = *reinterpret_cast<const float4*>(&As[kk][ty * 4]);
            float4 b4 = *reinterpret_cast<const float4*>(&Bs[kk][tx * 4]);
            float ar[4] = {a4.x, a4.y, a4.z, a4.w};
            float br[4] = {b4.x, b4.y, b4.z, b4.w};
#pragma unroll
            for (int i2 = 0; i2 < 4; ++i2)
#pragma unroll
                for (int j2 = 0; j2 < 4; ++j2)
                    acc[i2][j2] = fmaf(ar[i2], br[j2], acc[i2][j2]);
        }
        __syncthreads();
    }
#pragma unroll
    for (int i2 = 0; i2 < 4; ++i2) {
        int b = ty * 4 + i2;
        int n = n0 + tx * 4;
        float4 o = make_float4(acc[i2][0], acc[i2][1], acc[i2][2], acc[i2][3]);
        *reinterpret_cast<float4*>(qp + (size_t)(kc * 64 + b) * 512 + n) = o;
    }
}

// ------- fused attention + context: e=v.tanh(q+k), softmax, ctx -> x2h bf16 -------
__global__ __launch_bounds__(256)
void attn_ctx(const float* __restrict__ Whb, const float* __restrict__ vw,
              const float* __restrict__ V, const unsigned short* __restrict__ kb,
              float* __restrict__ ws) {
    const int b = blockIdx.x, tid = threadIdx.x;
    const float* qp = ws + OFF_QP;
    unsigned short* x2h = (unsigned short*)(ws + OFF_X2H);
    __shared__ float qs[512];
    __shared__ float es[196];
    __shared__ float red[256];
    __shared__ float as_[196];
    for (int j = tid; j < 512; j += 256) {
        float q = Whb[j];
#pragma unroll
        for (int p = 0; p < 4; ++p) q += qp[(size_t)(p * 64 + b) * 512 + j];
        qs[j] = q;
    }
    __syncthreads();
    const int w = tid >> 6, lane = tid & 63;
    // per-lane register copies of q,v slices (avoid strided LDS reads in the loop)
    float qr[8], vr[8];
#pragma unroll
    for (int j = 0; j < 8; ++j) {
        qr[j] = qs[lane * 8 + j];
        vr[j] = vw[lane * 8 + j];
    }
    for (int l = w; l < 196; l += 4) {
        const unsigned short* kr = kb + (size_t)(b * 196 + l) * 512 + lane * 8;
        ushort8 kv = *reinterpret_cast<const ushort8*>(kr);
        float s = 0.f;
#pragma unroll
        for (int j = 0; j < 8; ++j)
            s += vr[j] * ftanh(qr[j] + bf2f(kv[j]));
#pragma unroll
        for (int mm = 32; mm >= 1; mm >>= 1) s += __shfl_xor(s, mm);
        if (lane == 0) es[l] = s;
    }
    __syncthreads();
    float ev = (tid < 196) ? es[tid] : -1e30f;
    red[tid] = ev;
    __syncthreads();
    for (int s2 = 128; s2 > 0; s2 >>= 1) {
        if (tid < s2) red[tid] = fmaxf(red[tid], red[tid + s2]);
        __syncthreads();
    }
    float mx = red[0];
    __syncthreads();
    float p = (tid < 196) ? __expf(ev - mx) : 0.f;
    red[tid] = p;
    __syncthreads();
    for (int s2 = 128; s2 > 0; s2 >>= 1) {
        if (tid < s2) red[tid] += red[tid + s2];
        __syncthreads();
    }
    if (tid < 196) as_[tid] = p / red[0];
    __syncthreads();
    // ctx: each thread owns 8 consecutive channels
    const int c0 = tid * 8;
    const float* vp = V + (size_t)b * 196 * 2048 + c0;
    float a0=0,a1=0,a2=0,a3=0,a4=0,a5=0,a6=0,a7=0;
    for (int l = 0; l < 196; ++l) {
        float a = as_[l];
        float4 x = *reinterpret_cast<const float4*>(vp + (size_t)l * 2048);
        float4 y = *reinterpret_cast<const float4*>(vp + (size_t)l * 2048 + 4);
        a0 = fmaf(a, x.x, a0); a1 = fmaf(a, x.y, a1);
        a2 = fmaf(a, x.z, a2); a3 = fmaf(a, x.w, a3);
        a4 = fmaf(a, y.x, a4); a5 = fmaf(a, y.y, a5);
        a6 = fmaf(a, y.z, a6); a7 = fmaf(a, y.w, a7);
    }
    ushort8 o;
    o[0]=f2bf(a0); o[1]=f2bf(a1); o[2]=f2bf(a2); o[3]=f2bf(a3);
    o[4]=f2bf(a4); o[5]=f2bf(a5); o[6]=f2bf(a6); o[7]=f2bf(a7);
    *reinterpret_cast<ushort8*>(x2h + (size_t)b * 2560 + c0) = o;
}

// ------- gates partials via MFMA: part[kc] = x2h @ Wgh^T over K-chunk kc -------
// M=64 N=2048 K=2560; grid (32 n-tiles, 4 kc); tile 64x64, BK=32
__global__ __launch_bounds__(256)
void gates_mfma(const float* __restrict__ ws, const unsigned short* __restrict__ Wgh,
                float* __restrict__ part_out) {
    __shared__ unsigned short At[64 * 32];
    __shared__ unsigned short Bt[64 * 32];
    const unsigned short* x2h = (const unsigned short*)(ws + OFF_X2H);
    const int tid = threadIdx.x;
    const int lane = tid & 63, wave = tid >> 6;
    const int wr = wave >> 1, wc = wave & 1;
    const int n0 = blockIdx.x * 64;
    const int kc = blockIdx.y;
    const int srow = tid >> 2, skg = tid & 3;
    const unsigned short* ga = x2h + (size_t)srow * 2560 + kc * 640 + skg * 8;
    const unsigned short* gb = Wgh + (size_t)(n0 + srow) * 2560 + kc * 640 + skg * 8;
    const int ar0 = (wr * 32 + (lane & 15)) * 32 + (lane >> 4) * 8;
    const int br0 = (wc * 32 + (lane & 15)) * 32 + (lane >> 4) * 8;
    f32x4 acc[2][2] = {};
    for (int kt = 0; kt < 20; ++kt) {
        *reinterpret_cast<ushort8*>(&At[tid * 8]) = *reinterpret_cast<const ushort8*>(ga + kt * 32);
        *reinterpret_cast<ushort8*>(&Bt[tid * 8]) = *reinterpret_cast<const ushort8*>(gb + kt * 32);
        __syncthreads();
        bf16x8 af0 = *reinterpret_cast<const bf16x8*>(&At[ar0]);
        bf16x8 af1 = *reinterpret_cast<const bf16x8*>(&At[ar0 + 16 * 32]);
        bf16x8 bf0 = *reinterpret_cast<const bf16x8*>(&Bt[br0]);
        bf16x8 bf1 = *reinterpret_cast<const bf16x8*>(&Bt[br0 + 16 * 32]);
        acc[0][0] = __builtin_amdgcn_mfma_f32_16x16x32_bf16(af0, bf0, acc[0][0], 0, 0, 0);
        acc[0][1] = __builtin_amdgcn_mfma_f32_16x16x32_bf16(af0, bf1, acc[0][1], 0, 0, 0);
        acc[1][0] = __builtin_amdgcn_mfma_f32_16x16x32_bf16(af1, bf0, acc[1][0], 0, 0, 0);
        acc[1][1] = __builtin_amdgcn_mfma_f32_16x16x32_bf16(af1, bf1, acc[1][1], 0, 0, 0);
        __syncthreads();
    }
#pragma unroll
    for (int fi = 0; fi < 2; ++fi)
#pragma unroll
        for (int fj = 0; fj < 2; ++fj)
#pragma unroll
            for (int r = 0; r < 4; ++r) {
                int m = wr * 32 + fi * 16 + (lane >> 4) * 4 + r;   // batch row
                int n = n0 + wc * 32 + fj * 16 + (lane & 15);      // gate col
                part_out[(size_t)(kc * 64 + m) * 2048 + n] = acc[fi][fj][r];
            }
}

// ---------------- LSTM pointwise: reduce partials + ge -> h,c ----------------
__global__ __launch_bounds__(256)
void lstm_step(float* __restrict__ ws, const float* __restrict__ geb, int t) {
    const int b = blockIdx.x, tid = threadIdx.x;
    const float* ge = geb + (size_t)(t * 64 + b) * 2048;
    const float* part = ws + OFF_PART;
    float* h = ws + OFF_H;
    float* c = ws + OFF_C;
    unsigned short* x2h = (unsigned short*)(ws + OFF_X2H);
    float* hall = ws + OFF_HALL;
#pragma unroll
    for (int jj = 0; jj < 2; ++jj) {
        int j = tid + jj * 256;
        float ig = ge[j], fg = ge[512 + j], gg = ge[1024 + j], og = ge[1536 + j];
#pragma unroll
        for (int p = 0; p < 4; ++p) {
            const float* pp = part + (size_t)(p * 64 + b) * 2048;
            ig += pp[j]; fg += pp[512 + j]; gg += pp[1024 + j]; og += pp[1536 + j];
        }
        float cv = fsig(fg) * c[b * 512 + j] + fsig(ig) * ftanh(gg);
        float hv = fsig(og) * ftanh(cv);
        c[b * 512 + j] = cv;
        h[b * 512 + j] = hv;
        x2h[(size_t)b * 2560 + 2048 + j] = f2bf(hv);
        hall[(size_t)(t * 64 + b) * 512 + j] = hv;
    }
}

// ---------------- logits = hall @ out_w^T + out_b (MFMA bf16) ----------------
// M=1216 (19 t-tiles of 64) N=10000 K=512; grid (19, 157)
__global__ __launch_bounds__(256)
void gemm_logits_mfma(const float* __restrict__ outw, const float* __restrict__ outb,
                      const float* __restrict__ ws, float* __restrict__ out) {
    __shared__ unsigned short At[64 * 32];
    __shared__ unsigned short Bt[64 * 32];
    const float* hall = ws + OFF_HALL;
    const int tid = threadIdx.x;
    const int lane = tid & 63, wave = tid >> 6;
    const int wr = wave >> 1, wc = wave & 1;
    const int t = blockIdx.x;
    const int n0 = blockIdx.y * 64;
    const int srow = tid >> 2, skg = tid & 3;
    int brow = n0 + srow; if (brow > 9999) brow = 9999;
    const float* ga = hall + (size_t)(t * 64 + srow) * 512 + skg * 8;
    const float* gb = outw + (size_t)brow * 512 + skg * 8;
    const int ar0 = (wr * 32 + (lane & 15)) * 32 + (lane >> 4) * 8;
    const int br0 = (wc * 32 + (lane & 15)) * 32 + (lane >> 4) * 8;
    f32x4 acc[2][2] = {};
    for (int k0 = 0; k0 < 512; k0 += 32) {
        float4 a0 = *reinterpret_cast<const float4*>(ga + k0);
        float4 a1 = *reinterpret_cast<const float4*>(ga + k0 + 4);
        float4 b0 = *reinterpret_cast<const float4*>(gb + k0);
        float4 b1 = *reinterpret_cast<const float4*>(gb + k0 + 4);
        ushort8 ua, ub;
        ua[0]=f2bf(a0.x); ua[1]=f2bf(a0.y); ua[2]=f2bf(a0.z); ua[3]=f2bf(a0.w);
        ua[4]=f2bf(a1.x); ua[5]=f2bf(a1.y); ua[6]=f2bf(a1.z); ua[7]=f2bf(a1.w);
        ub[0]=f2bf(b0.x); ub[1]=f2bf(b0.y); ub[2]=f2bf(b0.z); ub[3]=f2bf(b0.w);
        ub[4]=f2bf(b1.x); ub[5]=f2bf(b1.y); ub[6]=f2bf(b1.z); ub[7]=f2bf(b1.w);
        *reinterpret_cast<ushort8*>(&At[tid * 8]) = ua;
        *reinterpret_cast<ushort8*>(&Bt[tid * 8]) = ub;
        __syncthreads();
        bf16x8 af0 = *reinterpret_cast<const bf16x8*>(&At[ar0]);
        bf16x8 af1 = *reinterpret_cast<const bf16x8*>(&At[ar0 + 16 * 32]);
        bf16x8 bf0 = *reinterpret_cast<const bf16x8*>(&Bt[br0]);
        bf16x8 bf1 = *reinterpret_cast<const bf16x8*>(&Bt[br0 + 16 * 32]);
        acc[0][0] = __builtin_amdgcn_mfma_f32_16x16x32_bf16(af0, bf0, acc[0][0], 0, 0, 0);
        acc[0][1] = __builtin_amdgcn_mfma_f32_16x16x32_bf16(af0, bf1, acc[0][1], 0, 0, 0);
        acc[1][0] = __builtin_amdgcn_mfma_f32_16x16x32_bf16(af1, bf0, acc[1][0], 0, 0, 0);
        acc[1][1] = __builtin_amdgcn_mfma_f32_16x16x32_bf16(af1, bf1, acc[1][1], 0, 0, 0);
        __syncthreads();
    }
#pragma unroll
    for (int fi = 0; fi < 2; ++fi)
#pragma unroll
        for (int fj = 0; fj < 2; ++fj)
#pragma unroll
            for (int r = 0; r < 4; ++r) {
                int b = wr * 32 + fi * 16 + (lane >> 4) * 4 + r;   // batch row
                int n = n0 + wc * 32 + fj * 16 + (lane & 15);
                if (n < 10000)
                    out[((size_t)b * 19 + t) * 10000 + n] = acc[fi][fj][r] + outb[n];
            }
}

extern "C" void kernel_launch(void* const* d_in, const int* in_sizes, int n_in,
                              void* d_out, int out_size, void* d_ws, size_t ws_size,
                              hipStream_t stream) {
    const float* V    = (const float*)d_in[0];
    const int*   caps = (const int*)d_in[1];
    const float* embW = (const float*)d_in[2];
    const float* Whw  = (const float*)d_in[3];
    const float* Whb  = (const float*)d_in[4];
    const float* Wvw  = (const float*)d_in[5];
    const float* Wvb  = (const float*)d_in[6];
    const float* vw   = (const float*)d_in[7];
    // d_in[8] = v_b: constant inside softmax -> cancels
    const float* Wih  = (const float*)d_in[9];
    const float* Whh  = (const float*)d_in[10];
    const float* bih  = (const float*)d_in[11];
    const float* bhh  = (const float*)d_in[12];
    const float* outw = (const float*)d_in[13];
    const float* outb = (const float*)d_in[14];
    float* ws  = (float*)d_ws;
    float* out = (float*)d_out;

    unsigned short* Wgh  = (unsigned short*)(out + D_WGH);
    float*          ge   = out + D_GE;
    unsigned short* kbuf = (unsigned short*)(out + D_KB);
    float*          part = ws + OFF_PART;

    init_state<<<dim3(64), dim3(256), 0, stream>>>(ws);
    conv_wg<<<dim3(2560), dim3(256), 0, stream>>>(Wih, Whh, Wgh);
    gemm_k_mfma<<<dim3(196, 8), dim3(256), 0, stream>>>(V, Wvw, Wvb, kbuf);
    gemm_emb<<<dim3(19, 32), dim3(256), 0, stream>>>(embW, caps, Wih, bih, bhh, ge);

    for (int t = 0; t < 19; ++t) {
        kq_gemm<<<dim3(8, 4), dim3(256), 0, stream>>>(Whw, ws);
        attn_ctx<<<dim3(64), dim3(256), 0, stream>>>(Whb, vw, V, kbuf, ws);
        gates_mfma<<<dim3(32, 4), dim3(256), 0, stream>>>(ws, Wgh, part);
        lstm_step<<<dim3(64), dim3(256), 0, stream>>>(ws, ge, t);
    }

    gemm_logits_mfma<<<dim3(19, 157), dim3(256), 0, stream>>>(outw, outb, ws, out);
}

// Round 5
// 1887.893 us; speedup vs baseline: 1.3713x; 1.0472x over previous
//
#include <hip/hip_runtime.h>

// B=64, L=196, CV=2048, T=20 (19 steps), VOCAB=10000, E=H=A=512, 4H=2048
// Round 5 = round 3 (proven) + ONE change: ctx split into its own 512-block kernel.

typedef __bf16 bf16x8 __attribute__((ext_vector_type(8)));
typedef float f32x4 __attribute__((ext_vector_type(4)));
typedef unsigned short ushort8 __attribute__((ext_vector_type(8)));

// ---------------- workspace layout (float offsets), ~5.75 MB ----------------
#define OFF_HALL 0ull                   // hall fp32 [19*64][512]  = 622592 f
#define OFF_X2H  622592ull              // x2h bf16 [64][2560]     = 81920 f-equiv
#define OFF_H    704512ull              // h fp32 [64][512]
#define OFF_C    737280ull              // c fp32 [64][512]
#define OFF_QP   770048ull              // q split-K partials fp32 [4][64][512]
#define OFF_PART 901120ull              // gates split-K partials fp32 [4][64][2048]
#define OFF_AB   1425408ull             // attention weights fp32 [64][196]
// end = 1,437,952 floats

// ---------------- d_out scrap layout (float offsets; dead before gemm_logits) ----
#define D_WGH 0ull                      // Wg bf16 [2048][2560] = 2,621,440 f-equiv
#define D_GE  2621440ull                // gates_emb fp32 [19*64][2048] = 2,490,368 f
#define D_KB  5111808ull                // k bf16 [12544][512] = 3,211,264 f-equiv
// end = 8,323,072 <= 12,160,000

__device__ __forceinline__ unsigned short f2bf(float f) {
    unsigned int u = __float_as_uint(f);
    unsigned int r = u + 0x7FFFu + ((u >> 16) & 1u);
    return (unsigned short)(r >> 16);
}
__device__ __forceinline__ float bf2f(unsigned short h) {
    return __uint_as_float(((unsigned int)h) << 16);
}
__device__ __forceinline__ float ftanh(float x) {
    x = fminf(fmaxf(x, -15.f), 15.f);
    float e = __expf(2.f * x);
    return (e - 1.f) / (e + 1.f);
}
__device__ __forceinline__ float fsig(float x) {
    x = fminf(fmaxf(x, -30.f), 30.f);
    return 1.f / (1.f + __expf(-x));
}

// ---------------- init: zero h, c, x2h h-part ----------------
__global__ void init_state(float* __restrict__ ws) {
    const int b = blockIdx.x, tid = threadIdx.x;
    float* h  = ws + OFF_H;
    float* c  = ws + OFF_C;
    unsigned short* x2h = (unsigned short*)(ws + OFF_X2H);
    for (int j = tid; j < 512; j += 256) {
        h[b * 512 + j] = 0.f;
        c[b * 512 + j] = 0.f;
        x2h[b * 2560 + 2048 + j] = 0;
    }
}

// ---------------- Wg bf16 = [Wih[:,512:] | Whh]  [2048][2560] ----------------
__global__ __launch_bounds__(256)
void conv_wg(const float* __restrict__ Wih, const float* __restrict__ Whh,
             unsigned short* __restrict__ Wgh) {
    const int idx = blockIdx.x * 256 + threadIdx.x;   // 2560 blocks, 8 elems each
    const int j = idx / 320;
    const int c0 = (idx - j * 320) * 8;
    const float* src;
    if (c0 < 2048) src = Wih + (size_t)j * 2560 + 512 + c0;
    else           src = Whh + (size_t)j * 512 + (c0 - 2048);
    float4 a = *reinterpret_cast<const float4*>(src);
    float4 b = *reinterpret_cast<const float4*>(src + 4);
    ushort8 o;
    o[0]=f2bf(a.x); o[1]=f2bf(a.y); o[2]=f2bf(a.z); o[3]=f2bf(a.w);
    o[4]=f2bf(b.x); o[5]=f2bf(b.y); o[6]=f2bf(b.z); o[7]=f2bf(b.w);
    *reinterpret_cast<ushort8*>(Wgh + (size_t)j * 2560 + c0) = o;
}

// ---------------- k = V @ Wv^T + bv  (MFMA bf16, out bf16) ----------------
// M=12544 N=512 K=2048, tile 64x64, BK=32, 4 waves (2x2 of 32x32)
__global__ __launch_bounds__(256)
void gemm_k_mfma(const float* __restrict__ V, const float* __restrict__ Wv,
                 const float* __restrict__ bv, unsigned short* __restrict__ kout) {
    __shared__ unsigned short At[64 * 32];
    __shared__ unsigned short Bt[64 * 32];
    const int tid = threadIdx.x;
    const int lane = tid & 63, wave = tid >> 6;
    const int wr = wave >> 1, wc = wave & 1;
    const int m0 = blockIdx.x * 64, n0 = blockIdx.y * 64;
    const int srow = tid >> 2, skg = tid & 3;
    const float* ga = V  + (size_t)(m0 + srow) * 2048 + skg * 8;
    const float* gb = Wv + (size_t)(n0 + srow) * 2048 + skg * 8;
    const int ar0 = (wr * 32 + (lane & 15)) * 32 + (lane >> 4) * 8;
    const int br0 = (wc * 32 + (lane & 15)) * 32 + (lane >> 4) * 8;
    f32x4 acc[2][2] = {};
    for (int k0 = 0; k0 < 2048; k0 += 32) {
        float4 a0 = *reinterpret_cast<const float4*>(ga + k0);
        float4 a1 = *reinterpret_cast<const float4*>(ga + k0 + 4);
        float4 b0 = *reinterpret_cast<const float4*>(gb + k0);
        float4 b1 = *reinterpret_cast<const float4*>(gb + k0 + 4);
        ushort8 ua, ub;
        ua[0]=f2bf(a0.x); ua[1]=f2bf(a0.y); ua[2]=f2bf(a0.z); ua[3]=f2bf(a0.w);
        ua[4]=f2bf(a1.x); ua[5]=f2bf(a1.y); ua[6]=f2bf(a1.z); ua[7]=f2bf(a1.w);
        ub[0]=f2bf(b0.x); ub[1]=f2bf(b0.y); ub[2]=f2bf(b0.z); ub[3]=f2bf(b0.w);
        ub[4]=f2bf(b1.x); ub[5]=f2bf(b1.y); ub[6]=f2bf(b1.z); ub[7]=f2bf(b1.w);
        *reinterpret_cast<ushort8*>(&At[tid * 8]) = ua;
        *reinterpret_cast<ushort8*>(&Bt[tid * 8]) = ub;
        __syncthreads();
        bf16x8 af0 = *reinterpret_cast<const bf16x8*>(&At[ar0]);
        bf16x8 af1 = *reinterpret_cast<const bf16x8*>(&At[ar0 + 16 * 32]);
        bf16x8 bf0 = *reinterpret_cast<const bf16x8*>(&Bt[br0]);
        bf16x8 bf1 = *reinterpret_cast<const bf16x8*>(&Bt[br0 + 16 * 32]);
        acc[0][0] = __builtin_amdgcn_mfma_f32_16x16x32_bf16(af0, bf0, acc[0][0], 0, 0, 0);
        acc[0][1] = __builtin_amdgcn_mfma_f32_16x16x32_bf16(af0, bf1, acc[0][1], 0, 0, 0);
        acc[1][0] = __builtin_amdgcn_mfma_f32_16x16x32_bf16(af1, bf0, acc[1][0], 0, 0, 0);
        acc[1][1] = __builtin_amdgcn_mfma_f32_16x16x32_bf16(af1, bf1, acc[1][1], 0, 0, 0);
        __syncthreads();
    }
#pragma unroll
    for (int fi = 0; fi < 2; ++fi)
#pragma unroll
        for (int fj = 0; fj < 2; ++fj)
#pragma unroll
            for (int r = 0; r < 4; ++r) {
                int m = m0 + wr * 32 + fi * 16 + (lane >> 4) * 4 + r;
                int n = n0 + wc * 32 + fj * 16 + (lane & 15);
                kout[(size_t)m * 512 + n] = f2bf(acc[fi][fj][r] + bv[n]);
            }
}

// ------- gates_emb[t,b,:] = embed[caps[b,t]] @ W_ih[:, :512]^T + b_ih + b_hh (fp32) -------
__global__ __launch_bounds__(256)
void gemm_emb(const float* __restrict__ embW, const int* __restrict__ caps,
              const float* __restrict__ Wih, const float* __restrict__ bih,
              const float* __restrict__ bhh, float* __restrict__ ge) {
    const int t = blockIdx.x;        // 19
    const int n0 = blockIdx.y * 64;  // 32
    __shared__ float As[32][68];
    __shared__ float Bs[32][68];
    __shared__ int capss[64];
    const int tid = threadIdx.x;
    const int tx = tid & 15, ty = tid >> 4;
    if (tid < 64) capss[tid] = caps[tid * 20 + t];
    __syncthreads();
    float acc[4][4] = {{0.f}};
    for (int k0 = 0; k0 < 512; k0 += 32) {
#pragma unroll
        for (int i = 0; i < 2; ++i) {
            int idx = tid + i * 256;
            int m = idx >> 3, cc = idx & 7;
            float4 av = *reinterpret_cast<const float4*>(embW + (size_t)capss[m] * 512 + k0 + cc * 4);
            As[cc * 4 + 0][m] = av.x; As[cc * 4 + 1][m] = av.y;
            As[cc * 4 + 2][m] = av.z; As[cc * 4 + 3][m] = av.w;
            float4 bw = *reinterpret_cast<const float4*>(Wih + (size_t)(n0 + m) * 2560 + k0 + cc * 4);
            Bs[cc * 4 + 0][m] = bw.x; Bs[cc * 4 + 1][m] = bw.y;
            Bs[cc * 4 + 2][m] = bw.z; Bs[cc * 4 + 3][m] = bw.w;
        }
        __syncthreads();
#pragma unroll
        for (int kk = 0; kk < 32; ++kk) {
            float4 a4 = *reinterpret_cast<const float4*>(&As[kk][ty * 4]);
            float4 b4 = *reinterpret_cast<const float4*>(&Bs[kk][tx * 4]);
            float ar[4] = {a4.x, a4.y, a4.z, a4.w};
            float br[4] = {b4.x, b4.y, b4.z, b4.w};
#pragma unroll
            for (int i2 = 0; i2 < 4; ++i2)
#pragma unroll
                for (int j2 = 0; j2 < 4; ++j2)
                    acc[i2][j2] = fmaf(ar[i2], br[j2], acc[i2][j2]);
        }
        __syncthreads();
    }
#pragma unroll
    for (int i2 = 0; i2 < 4; ++i2) {
        int m = ty * 4 + i2;
        int n = n0 + tx * 4;
        float4 o;
        o.x = acc[i2][0] + bih[n + 0] + bhh[n + 0];
        o.y = acc[i2][1] + bih[n + 1] + bhh[n + 1];
        o.z = acc[i2][2] + bih[n + 2] + bhh[n + 2];
        o.w = acc[i2][3] + bih[n + 3] + bhh[n + 3];
        *reinterpret_cast<float4*>(ge + (size_t)(t * 64 + m) * 2048 + n) = o;
    }
}

// ---------------- q partials (fp32): qp[p] = h @ Wh^T over K-chunk p ----------------
__global__ __launch_bounds__(256)
void kq_gemm(const float* __restrict__ Whw, float* __restrict__ ws) {
    const float* h = ws + OFF_H;
    float* qp = ws + OFF_QP;
    const int n0 = blockIdx.x * 64;  // 8
    const int kc = blockIdx.y;       // 4
    __shared__ float As[32][68];
    __shared__ float Bs[32][68];
    const int tid = threadIdx.x;
    const int tx = tid & 15, ty = tid >> 4;
    float acc[4][4] = {{0.f}};
    for (int kt = 0; kt < 4; ++kt) {
        int kb = kc * 128 + kt * 32;
#pragma unroll
        for (int i = 0; i < 2; ++i) {
            int idx = tid + i * 256;
            int m = idx >> 3, cc = idx & 7;
            float4 av = *reinterpret_cast<const float4*>(h + (size_t)m * 512 + kb + cc * 4);
            As[cc * 4 + 0][m] = av.x; As[cc * 4 + 1][m] = av.y;
            As[cc * 4 + 2][m] = av.z; As[cc * 4 + 3][m] = av.w;
            float4 bw = *reinterpret_cast<const float4*>(Whw + (size_t)(n0 + m) * 512 + kb + cc * 4);
            Bs[cc * 4 + 0][m] = bw.x; Bs[cc * 4 + 1][m] = bw.y;
            Bs[cc * 4 + 2][m] = bw.z; Bs[cc * 4 + 3][m] = bw.w;
        }
        __syncthreads();
#pragma unroll
        for (int kk = 0; kk < 32; ++kk) {
            float4 a4 = *reinterpret_cast<const float4*>(&As[kk][ty * 4]);
            float4 b4 = *reinterpret_cast<const float4*>(&Bs[kk][tx * 4]);
            float ar[4] = {a4.x, a4.y, a4.z, a4.w};
            float br[4] = {b4.x, b4.y, b4.z, b4.w};
#pragma unroll
            for (int i2 = 0; i2 < 4; ++i2)
#pragma unroll
                for (int j2 = 0; j2 < 4; ++j2)
                    acc[i2][j2] = fmaf(ar[i2], br[j2], acc[i2][j2]);
        }
        __syncthreads();
    }
#pragma unroll
    for (int i2 = 0; i2 < 4; ++i2) {
        int b = ty * 4 + i2;
        int n = n0 + tx * 4;
        float4 o = make_float4(acc[i2][0], acc[i2][1], acc[i2][2], acc[i2][3]);
        *reinterpret_cast<float4*>(qp + (size_t)(kc * 64 + b) * 512 + n) = o;
    }
}

// ------- attention: q = sum(qp)+Whb ; e = v.tanh(q+k) ; softmax -> abuf -------
__global__ __launch_bounds__(256)
void attn_step(const float* __restrict__ Whb, const float* __restrict__ vw,
               const unsigned short* __restrict__ kb, float* __restrict__ ws) {
    const int b = blockIdx.x, tid = threadIdx.x;
    const float* qp = ws + OFF_QP;
    float* abuf = ws + OFF_AB;
    __shared__ float qs[512];
    __shared__ float es[196];
    __shared__ float red[256];
    for (int j = tid; j < 512; j += 256) {
        float q = Whb[j];
#pragma unroll
        for (int p = 0; p < 4; ++p) q += qp[(size_t)(p * 64 + b) * 512 + j];
        qs[j] = q;
    }
    __syncthreads();
    const int w = tid >> 6, lane = tid & 63;
    float qr[8], vr[8];
#pragma unroll
    for (int j = 0; j < 8; ++j) {
        qr[j] = qs[lane * 8 + j];
        vr[j] = vw[lane * 8 + j];
    }
    for (int l = w; l < 196; l += 4) {
        const unsigned short* kr = kb + (size_t)(b * 196 + l) * 512 + lane * 8;
        ushort8 kv = *reinterpret_cast<const ushort8*>(kr);
        float s = 0.f;
#pragma unroll
        for (int j = 0; j < 8; ++j)
            s += vr[j] * ftanh(qr[j] + bf2f(kv[j]));
#pragma unroll
        for (int mm = 32; mm >= 1; mm >>= 1) s += __shfl_xor(s, mm);
        if (lane == 0) es[l] = s;
    }
    __syncthreads();
    float ev = (tid < 196) ? es[tid] : -1e30f;
    red[tid] = ev;
    __syncthreads();
    for (int s2 = 128; s2 > 0; s2 >>= 1) {
        if (tid < s2) red[tid] = fmaxf(red[tid], red[tid + s2]);
        __syncthreads();
    }
    float mx = red[0];
    __syncthreads();
    float p = (tid < 196) ? __expf(ev - mx) : 0.f;
    red[tid] = p;
    __syncthreads();
    for (int s2 = 128; s2 > 0; s2 >>= 1) {
        if (tid < s2) red[tid] += red[tid + s2];
        __syncthreads();
    }
    if (tid < 196) abuf[b * 196 + tid] = p / red[0];
}

// ---------------- ctx[b,c] = sum_l a[b,l] V[b,l,c] -> x2h bf16 (512 blocks) ----------------
__global__ __launch_bounds__(256)
void ctx_wide(const float* __restrict__ V, float* __restrict__ ws) {
    const int b = blockIdx.y, tid = threadIdx.x;
    const int c = blockIdx.x * 256 + tid;
    const float* abuf = ws + OFF_AB;
    unsigned short* x2h = (unsigned short*)(ws + OFF_X2H);
    __shared__ float as_[196];
    if (tid < 196) as_[tid] = abuf[b * 196 + tid];
    __syncthreads();
    const float* vb = V + (size_t)b * 196 * 2048 + c;
    float a0 = 0.f, a1 = 0.f, a2 = 0.f, a3 = 0.f;
    for (int l = 0; l < 196; l += 4) {
        a0 = fmaf(as_[l + 0], vb[(size_t)(l + 0) * 2048], a0);
        a1 = fmaf(as_[l + 1], vb[(size_t)(l + 1) * 2048], a1);
        a2 = fmaf(as_[l + 2], vb[(size_t)(l + 2) * 2048], a2);
        a3 = fmaf(as_[l + 3], vb[(size_t)(l + 3) * 2048], a3);
    }
    x2h[(size_t)b * 2560 + c] = f2bf((a0 + a1) + (a2 + a3));
}

// ------- gates partials via MFMA: part[kc] = x2h @ Wgh^T over K-chunk kc -------
__global__ __launch_bounds__(256)
void gates_mfma(const float* __restrict__ ws, const unsigned short* __restrict__ Wgh,
                float* __restrict__ part_out) {
    __shared__ unsigned short At[64 * 32];
    __shared__ unsigned short Bt[64 * 32];
    const unsigned short* x2h = (const unsigned short*)(ws + OFF_X2H);
    const int tid = threadIdx.x;
    const int lane = tid & 63, wave = tid >> 6;
    const int wr = wave >> 1, wc = wave & 1;
    const int n0 = blockIdx.x * 64;
    const int kc = blockIdx.y;
    const int srow = tid >> 2, skg = tid & 3;
    const unsigned short* ga = x2h + (size_t)srow * 2560 + kc * 640 + skg * 8;
    const unsigned short* gb = Wgh + (size_t)(n0 + srow) * 2560 + kc * 640 + skg * 8;
    const int ar0 = (wr * 32 + (lane & 15)) * 32 + (lane >> 4) * 8;
    const int br0 = (wc * 32 + (lane & 15)) * 32 + (lane >> 4) * 8;
    f32x4 acc[2][2] = {};
    for (int kt = 0; kt < 20; ++kt) {
        *reinterpret_cast<ushort8*>(&At[tid * 8]) = *reinterpret_cast<const ushort8*>(ga + kt * 32);
        *reinterpret_cast<ushort8*>(&Bt[tid * 8]) = *reinterpret_cast<const ushort8*>(gb + kt * 32);
        __syncthreads();
        bf16x8 af0 = *reinterpret_cast<const bf16x8*>(&At[ar0]);
        bf16x8 af1 = *reinterpret_cast<const bf16x8*>(&At[ar0 + 16 * 32]);
        bf16x8 bf0 = *reinterpret_cast<const bf16x8*>(&Bt[br0]);
        bf16x8 bf1 = *reinterpret_cast<const bf16x8*>(&Bt[br0 + 16 * 32]);
        acc[0][0] = __builtin_amdgcn_mfma_f32_16x16x32_bf16(af0, bf0, acc[0][0], 0, 0, 0);
        acc[0][1] = __builtin_amdgcn_mfma_f32_16x16x32_bf16(af0, bf1, acc[0][1], 0, 0, 0);
        acc[1][0] = __builtin_amdgcn_mfma_f32_16x16x32_bf16(af1, bf0, acc[1][0], 0, 0, 0);
        acc[1][1] = __builtin_amdgcn_mfma_f32_16x16x32_bf16(af1, bf1, acc[1][1], 0, 0, 0);
        __syncthreads();
    }
#pragma unroll
    for (int fi = 0; fi < 2; ++fi)
#pragma unroll
        for (int fj = 0; fj < 2; ++fj)
#pragma unroll
            for (int r = 0; r < 4; ++r) {
                int m = wr * 32 + fi * 16 + (lane >> 4) * 4 + r;   // batch row
                int n = n0 + wc * 32 + fj * 16 + (lane & 15);      // gate col
                part_out[(size_t)(kc * 64 + m) * 2048 + n] = acc[fi][fj][r];
            }
}

// ---------------- LSTM pointwise: reduce partials + ge -> h,c ----------------
__global__ __launch_bounds__(256)
void lstm_step(float* __restrict__ ws, const float* __restrict__ geb, int t) {
    const int b = blockIdx.x, tid = threadIdx.x;
    const float* ge = geb + (size_t)(t * 64 + b) * 2048;
    const float* part = ws + OFF_PART;
    float* h = ws + OFF_H;
    float* c = ws + OFF_C;
    unsigned short* x2h = (unsigned short*)(ws + OFF_X2H);
    float* hall = ws + OFF_HALL;
#pragma unroll
    for (int jj = 0; jj < 2; ++jj) {
        int j = tid + jj * 256;
        float ig = ge[j], fg = ge[512 + j], gg = ge[1024 + j], og = ge[1536 + j];
#pragma unroll
        for (int p = 0; p < 4; ++p) {
            const float* pp = part + (size_t)(p * 64 + b) * 2048;
            ig += pp[j]; fg += pp[512 + j]; gg += pp[1024 + j]; og += pp[1536 + j];
        }
        float cv = fsig(fg) * c[b * 512 + j] + fsig(ig) * ftanh(gg);
        float hv = fsig(og) * ftanh(cv);
        c[b * 512 + j] = cv;
        h[b * 512 + j] = hv;
        x2h[(size_t)b * 2560 + 2048 + j] = f2bf(hv);
        hall[(size_t)(t * 64 + b) * 512 + j] = hv;
    }
}

// ---------------- logits = hall @ out_w^T + out_b (MFMA bf16) ----------------
// M=1216 (19 t-tiles of 64) N=10000 K=512; grid (19, 157)
__global__ __launch_bounds__(256)
void gemm_logits_mfma(const float* __restrict__ outw, const float* __restrict__ outb,
                      const float* __restrict__ ws, float* __restrict__ out) {
    __shared__ unsigned short At[64 * 32];
    __shared__ unsigned short Bt[64 * 32];
    const float* hall = ws + OFF_HALL;
    const int tid = threadIdx.x;
    const int lane = tid & 63, wave = tid >> 6;
    const int wr = wave >> 1, wc = wave & 1;
    const int t = blockIdx.x;
    const int n0 = blockIdx.y * 64;
    const int srow = tid >> 2, skg = tid & 3;
    int brow = n0 + srow; if (brow > 9999) brow = 9999;
    const float* ga = hall + (size_t)(t * 64 + srow) * 512 + skg * 8;
    const float* gb = outw + (size_t)brow * 512 + skg * 8;
    const int ar0 = (wr * 32 + (lane & 15)) * 32 + (lane >> 4) * 8;
    const int br0 = (wc * 32 + (lane & 15)) * 32 + (lane >> 4) * 8;
    f32x4 acc[2][2] = {};
    for (int k0 = 0; k0 < 512; k0 += 32) {
        float4 a0 = *reinterpret_cast<const float4*>(ga + k0);
        float4 a1 = *reinterpret_cast<const float4*>(ga + k0 + 4);
        float4 b0 = *reinterpret_cast<const float4*>(gb + k0);
        float4 b1 = *reinterpret_cast<const float4*>(gb + k0 + 4);
        ushort8 ua, ub;
        ua[0]=f2bf(a0.x); ua[1]=f2bf(a0.y); ua[2]=f2bf(a0.z); ua[3]=f2bf(a0.w);
        ua[4]=f2bf(a1.x); ua[5]=f2bf(a1.y); ua[6]=f2bf(a1.z); ua[7]=f2bf(a1.w);
        ub[0]=f2bf(b0.x); ub[1]=f2bf(b0.y); ub[2]=f2bf(b0.z); ub[3]=f2bf(b0.w);
        ub[4]=f2bf(b1.x); ub[5]=f2bf(b1.y); ub[6]=f2bf(b1.z); ub[7]=f2bf(b1.w);
        *reinterpret_cast<ushort8*>(&At[tid * 8]) = ua;
        *reinterpret_cast<ushort8*>(&Bt[tid * 8]) = ub;
        __syncthreads();
        bf16x8 af0 = *reinterpret_cast<const bf16x8*>(&At[ar0]);
        bf16x8 af1 = *reinterpret_cast<const bf16x8*>(&At[ar0 + 16 * 32]);
        bf16x8 bf0 = *reinterpret_cast<const bf16x8*>(&Bt[br0]);
        bf16x8 bf1 = *reinterpret_cast<const bf16x8*>(&Bt[br0 + 16 * 32]);
        acc[0][0] = __builtin_amdgcn_mfma_f32_16x16x32_bf16(af0, bf0, acc[0][0], 0, 0, 0);
        acc[0][1] = __builtin_amdgcn_mfma_f32_16x16x32_bf16(af0, bf1, acc[0][1], 0, 0, 0);
        acc[1][0] = __builtin_amdgcn_mfma_f32_16x16x32_bf16(af1, bf0, acc[1][0], 0, 0, 0);
        acc[1][1] = __builtin_amdgcn_mfma_f32_16x16x32_bf16(af1, bf1, acc[1][1], 0, 0, 0);
        __syncthreads();
    }
#pragma unroll
    for (int fi = 0; fi < 2; ++fi)
#pragma unroll
        for (int fj = 0; fj < 2; ++fj)
#pragma unroll
            for (int r = 0; r < 4; ++r) {
                int b = wr * 32 + fi * 16 + (lane >> 4) * 4 + r;   // batch row
                int n = n0 + wc * 32 + fj * 16 + (lane & 15);
                if (n < 10000)
                    out[((size_t)b * 19 + t) * 10000 + n] = acc[fi][fj][r] + outb[n];
            }
}

extern "C" void kernel_launch(void* const* d_in, const int* in_sizes, int n_in,
                              void* d_out, int out_size, void* d_ws, size_t ws_size,
                              hipStream_t stream) {
    const float* V    = (const float*)d_in[0];
    const int*   caps = (const int*)d_in[1];
    const float* embW = (const float*)d_in[2];
    const float* Whw  = (const float*)d_in[3];
    const float* Whb  = (const float*)d_in[4];
    const float* Wvw  = (const float*)d_in[5];
    const float* Wvb  = (const float*)d_in[6];
    const float* vw   = (const float*)d_in[7];
    // d_in[8] = v_b: constant inside softmax -> cancels
    const float* Wih  = (const float*)d_in[9];
    const float* Whh  = (const float*)d_in[10];
    const float* bih  = (const float*)d_in[11];
    const float* bhh  = (const float*)d_in[12];
    const float* outw = (const float*)d_in[13];
    const float* outb = (const float*)d_in[14];
    float* ws  = (float*)d_ws;
    float* out = (float*)d_out;

    unsigned short* Wgh  = (unsigned short*)(out + D_WGH);
    float*          ge   = out + D_GE;
    unsigned short* kbuf = (unsigned short*)(out + D_KB);
    float*          part = ws + OFF_PART;

    init_state<<<dim3(64), dim3(256), 0, stream>>>(ws);
    conv_wg<<<dim3(2560), dim3(256), 0, stream>>>(Wih, Whh, Wgh);
    gemm_k_mfma<<<dim3(196, 8), dim3(256), 0, stream>>>(V, Wvw, Wvb, kbuf);
    gemm_emb<<<dim3(19, 32), dim3(256), 0, stream>>>(embW, caps, Wih, bih, bhh, ge);

    for (int t = 0; t < 19; ++t) {
        kq_gemm<<<dim3(8, 4), dim3(256), 0, stream>>>(Whw, ws);
        attn_step<<<dim3(64), dim3(256), 0, stream>>>(Whb, vw, kbuf, ws);
        ctx_wide<<<dim3(8, 64), dim3(256), 0, stream>>>(V, ws);
        gates_mfma<<<dim3(32, 4), dim3(256), 0, stream>>>(ws, Wgh, part);
        lstm_step<<<dim3(64), dim3(256), 0, stream>>>(ws, ge, t);
    }

    gemm_logits_mfma<<<dim3(19, 157), dim3(256), 0, stream>>>(outw, outb, ws, out);
}